// Round 13
// baseline (375.851 us; speedup 1.0000x reference)
//
#include <hip/hip_runtime.h>
#include <hip/hip_bf16.h>
#include <stdint.h>

#define HID     128
#define OUTC    10
#define NGRAPH  512
#define NGROUP  256        // one writer block per group (1 block/CU)
#define PSIZE   256        // nodes per bin
#define CAP     64         // entries per (bin,group) region (mean 16, +12 sigma), 256B aligned
#define NBIN_MX 400        // compile-time bound for LDS arrays (NBIN=391 for n=100000)

using bf16x8 = __attribute__((ext_vector_type(8))) short;
using f32x4  = __attribute__((ext_vector_type(4))) float;
using u32x4  = __attribute__((ext_vector_type(4))) uint32_t;

__device__ __forceinline__ short f2bf(float f) {
    __hip_bfloat16 h = __float2bfloat16(f);
    return *reinterpret_cast<short*>(&h);
}
__device__ __forceinline__ float bf2f(short s) {
    union { uint32_t u; float f; } x; x.u = ((uint32_t)(uint16_t)s) << 16; return x.f;
}
__device__ __forceinline__ float bflo(uint32_t v) {
    union { uint32_t u; float f; } x; x.u = v << 16; return x.f;
}
__device__ __forceinline__ float bfhi(uint32_t v) {
    union { uint32_t u; float f; } x; x.u = v & 0xffff0000u; return x.f;
}
__device__ __forceinline__ uint32_t pk2(float lo, float hi) {
    return (uint32_t)(uint16_t)f2bf(lo) | ((uint32_t)(uint16_t)f2bf(hi) << 16);
}

// Inline int64-vs-int32 layout detection (wave-wide ballot on odd words).
__device__ __forceinline__ int detect_f64(const int* __restrict__ ei) {
    int lane = threadIdx.x & 63;
    int v = ei[2 * lane + 1];
    unsigned long long b = __ballot(v == 0);
    return (b == ~0ULL) ? 1 : 0;
}

__device__ __forceinline__ int fetch_idx(const int* __restrict__ p, long j, int f64) {
    return p[f64 ? (j << 1) : j];
}

// ---------------------------------------------------------------------------
// prep: blocks 0-2 -> weight transpose+split; remaining -> boundary detect.
// (cnt no longer needs zeroing: scatter's flush writes every cell.)
// ---------------------------------------------------------------------------
__global__ void __launch_bounds__(256) prep_kernel(
        const int* __restrict__ ei, const int* __restrict__ batch,
        const float* __restrict__ W0, const float* __restrict__ W1,
        const float* __restrict__ W2, short* __restrict__ Wt,
        int* __restrict__ gstart, int n) {
    __shared__ float Ws[64][129];
    int bid = blockIdx.x;
    const int tid = threadIdx.x;

    if (bid < 3) {                                   // ---- weight prep
        const float* W = (bid == 0) ? W0 : (bid == 1) ? W1 : W2;
        short* hi = Wt + (size_t)bid * 2 * HID * HID;
        short* lo = hi + HID * HID;
        for (int half = 0; half < 2; ++half) {
            const int kbase = half * 64;
#pragma unroll
            for (int it = 0; it < 8; ++it) {
                int idx = (tid + it * 256) * 4;
                int k = idx >> 7, c = idx & 127;
                float4 v = *(const float4*)(W + (size_t)(kbase + k) * HID + c);
                Ws[k][c] = v.x; Ws[k][c + 1] = v.y; Ws[k][c + 2] = v.z; Ws[k][c + 3] = v.w;
            }
            __syncthreads();
            const int k2 = tid & 63;
            const int cb = tid >> 6;
#pragma unroll
            for (int it = 0; it < 32; ++it) {
                int c = cb + it * 4;
                float w = Ws[k2][c];
                short h = f2bf(w);
                hi[(size_t)c * HID + kbase + k2] = h;
                lo[(size_t)c * HID + kbase + k2] = f2bf(w - bf2f(h));
            }
            __syncthreads();
        }
        return;
    }
    bid -= 3;
    // ---- boundary detection (batch sorted)
    const int f = detect_f64(ei);
    int i = bid * 256 + tid;
    if (i >= n) return;
    int b  = fetch_idx(batch, i, f);
    int bp = (i == 0) ? -1 : fetch_idx(batch, i - 1, f);
    for (int g = bp + 1; g <= b; ++g) gstart[g] = i;
    if (i == n - 1) {
        for (int g = b + 1; g <= NGRAPH; ++g) gstart[g] = n;
    }
}

// ---------------------------------------------------------------------------
// CSR pass A: single-writer LDS-bucketed scatter. Block g streams its
// contiguous edge chunk once, inserts into LDS buckets (LDS atomics only),
// then flushes to exclusive 256B-aligned regions. Zero global atomics.
// entry = src | dst_local<<20
// ---------------------------------------------------------------------------
__global__ void __launch_bounds__(512) bin_scatter_kernel(
        const int* __restrict__ ei, int* __restrict__ cnt,
        uint32_t* __restrict__ binned, long E, int NBIN) {
    __shared__ int      lcnt[NBIN_MX];
    __shared__ uint32_t lbin[NBIN_MX * CAP];        // 100 KB
    const int g   = blockIdx.x;
    const int tid = threadIdx.x;
    const int f   = detect_f64(ei);
    for (int b = tid; b < NBIN; b += 512) lcnt[b] = 0;
    __syncthreads();
    const long chunk = (E + gridDim.x - 1) / gridDim.x;
    const long e0 = (long)g * chunk;
    const long e1 = (e0 + chunk < E) ? e0 + chunk : E;
    for (long e = e0 + tid; e < e1; e += 512) {
        int s = fetch_idx(ei, e, f);
        int d = fetch_idx(ei, E + e, f);
        int b = d >> 8;
        int p = atomicAdd(&lcnt[b], 1);
        if (p < CAP)
            lbin[b * CAP + p] = (uint32_t)s | ((uint32_t)(d & (PSIZE - 1)) << 20);
    }
    __syncthreads();
    const int wv = tid >> 6, lane = tid & 63;
    for (int b = wv; b < NBIN; b += 8) {
        int c = min(lcnt[b], CAP);
        uint32_t* __restrict__ dst = binned + ((size_t)b * NGROUP + g) * CAP;
        for (int i = lane; i < c; i += 64) dst[i] = lbin[b * CAP + i];
        if (lane == 0) cnt[b * NGROUP + g] = c;
    }
}

// ---------------------------------------------------------------------------
// bin totals (wave-per-bin coalesced sums over 256 group counts) + scan.
// ---------------------------------------------------------------------------
__global__ void __launch_bounds__(1024) binscan_kernel(
        const int* __restrict__ cnt, int* __restrict__ bofs, int NBIN) {
    __shared__ int stot[NBIN_MX];
    __shared__ int wsum[16];
    const int tid  = threadIdx.x;
    const int lane = tid & 63;
    const int wid  = tid >> 6;
    for (int b = wid; b < NBIN; b += 16) {
        int s = 0;
#pragma unroll
        for (int i = 0; i < NGROUP / 64; ++i) s += cnt[b * NGROUP + lane + i * 64];
#pragma unroll
        for (int d = 1; d < 64; d <<= 1) s += __shfl_xor(s, d, 64);
        if (lane == 0) stot[b] = s;
    }
    __syncthreads();
    int v = (tid < NBIN) ? stot[tid] : 0;
    int inc = v;
#pragma unroll
    for (int d = 1; d < 64; d <<= 1) {
        int t = __shfl_up(inc, d, 64);
        if (lane >= d) inc += t;
    }
    if (lane == 63) wsum[wid] = inc;
    __syncthreads();
    if (wid == 0) {
        int ws = (lane < 16) ? wsum[lane] : 0;
        int winc = ws;
#pragma unroll
        for (int d = 1; d < 16; d <<= 1) {
            int t = __shfl_up(winc, d, 64);
            if (lane >= d) winc += t;
        }
        if (lane < 16) wsum[lane] = winc - ws;
    }
    __syncthreads();
    int excl = wsum[wid] + (inc - v);
    if (tid <= NBIN) bofs[tid] = excl;
}

// ---------------------------------------------------------------------------
// CSR pass B: one block per bin; LDS histogram -> scan -> scatter; ofs + dinv.
// (bin-major region layout: bin b's 256 regions are contiguous.)
// ---------------------------------------------------------------------------
__global__ void __launch_bounds__(512) bin_build_kernel(
        const uint32_t* __restrict__ binned, const int* __restrict__ cnt,
        const int* __restrict__ bofs, int* __restrict__ ofs,
        float* __restrict__ dinv, int* __restrict__ col,
        int n, int NBIN, long E) {
    __shared__ int lcnt[PSIZE];
    __shared__ int lofs[PSIZE];
    __shared__ int lrank[PSIZE];
    __shared__ int wtot[4];
    const int b    = blockIdx.x;
    const int v0   = b * PSIZE;
    const int nn   = min(PSIZE, n - v0);
    const int tid  = threadIdx.x;
    const int wv   = tid >> 6;
    const int lane = tid & 63;
    if (tid < PSIZE) { lcnt[tid] = 0; lrank[tid] = 0; }
    __syncthreads();
    for (int sg = wv; sg < NGROUP; sg += 8) {
        const int c = min(cnt[b * NGROUP + sg], CAP);
        const uint32_t* __restrict__ src = binned + ((size_t)b * NGROUP + sg) * CAP;
        for (int i = lane; i < c; i += 64)
            atomicAdd(&lcnt[src[i] >> 20], 1);
    }
    __syncthreads();
    if (tid < PSIZE) {               // 4-wave two-level scan of lcnt
        int v = lcnt[tid];
        int inc = v;
#pragma unroll
        for (int d = 1; d < 64; d <<= 1) {
            int t = __shfl_up(inc, d, 64);
            if (lane >= d) inc += t;
        }
        if (lane == 63) wtot[wv] = inc;
        lofs[tid] = inc - v;
    }
    __syncthreads();
    if (tid < PSIZE) {
        int add = 0;
#pragma unroll
        for (int k = 0; k < 4; ++k) if (k < wv) add += wtot[k];
        lofs[tid] += add;
    }
    __syncthreads();
    const int base = bofs[b];
    for (int sg = wv; sg < NGROUP; sg += 8) {
        const int c = min(cnt[b * NGROUP + sg], CAP);
        const uint32_t* __restrict__ src = binned + ((size_t)b * NGROUP + sg) * CAP;
        for (int i = lane; i < c; i += 64) {
            uint32_t v = src[i];
            int dl = (int)(v >> 20);
            int rk = atomicAdd(&lrank[dl], 1);
            col[base + lofs[dl] + rk] = (int)(v & 0xFFFFFu);
        }
    }
    if (tid < nn) {
        ofs[v0 + tid]  = base + lofs[tid];
        dinv[v0 + tid] = rsqrtf((float)lcnt[tid] + 1.0f);
    }
    if (tid == 0 && v0 + nn == n) ofs[n] = (int)E;
}

// ---------------------------------------------------------------------------
// hs = bf16( (A @ W) * dinv[:,None] ) — MFMA bf16, split-W hi+lo.
// A tile staged once in LDS, chunk-XOR swizzle.  [round-12 validated]
// ---------------------------------------------------------------------------
template<bool AFP32>
__global__ void __launch_bounds__(256) gemm_hs_kernel(
        const void* __restrict__ Ap, const short* __restrict__ Wt,
        const float* __restrict__ dinv, short* __restrict__ hs, int n) {
    __shared__ __attribute__((aligned(16))) short As[128 * 128];  // 32 KB
    const short* __restrict__ Bh = Wt;
    const short* __restrict__ Bl = Wt + HID * HID;
    const int tid = threadIdx.x;
    const int w  = tid >> 6;
    const int l  = tid & 63;
    const int lr = l & 15;
    const int kq = l >> 4;
    const int r0 = blockIdx.x * 128;

    const float* Af = (const float*)Ap;
    const short* Ab = (const short*)Ap;

#pragma unroll
    for (int it = 0; it < 8; ++it) {
        int ci  = tid + it * 256;
        int row = ci >> 4, c = ci & 15;
        int rg  = r0 + row; if (rg >= n) rg = n - 1;
        bf16x8 tv;
        if (AFP32) {
            const float* ap = Af + (size_t)rg * HID + c * 8;
            float4 f0 = *(const float4*)ap;
            float4 f1 = *(const float4*)(ap + 4);
            tv[0] = f2bf(f0.x); tv[1] = f2bf(f0.y); tv[2] = f2bf(f0.z); tv[3] = f2bf(f0.w);
            tv[4] = f2bf(f1.x); tv[5] = f2bf(f1.y); tv[6] = f2bf(f1.z); tv[7] = f2bf(f1.w);
        } else {
            tv = *(const bf16x8*)(Ab + (size_t)rg * HID + c * 8);
        }
        *(bf16x8*)(As + row * 128 + ((c ^ (row & 15)) << 3)) = tv;
    }
    __syncthreads();

    f32x4 acc[8][2] = {};
    const int col0 = w * 32 + lr;
    const int col1 = w * 32 + 16 + lr;

#pragma unroll
    for (int ks = 0; ks < 4; ++ks) {
        const int k0 = ks * 32 + kq * 8;
        bf16x8 a[8];
#pragma unroll
        for (int rf = 0; rf < 8; ++rf) {
            int row = rf * 16 + lr;
            a[rf] = *(const bf16x8*)(As + row * 128 + (((ks * 4 + kq) ^ lr) << 3));
        }
        bf16x8 bh0 = *(const bf16x8*)(Bh + (size_t)col0 * HID + k0);
        bf16x8 bh1 = *(const bf16x8*)(Bh + (size_t)col1 * HID + k0);
        bf16x8 bl0 = *(const bf16x8*)(Bl + (size_t)col0 * HID + k0);
        bf16x8 bl1 = *(const bf16x8*)(Bl + (size_t)col1 * HID + k0);
#pragma unroll
        for (int rf = 0; rf < 8; ++rf) {
            acc[rf][0] = __builtin_amdgcn_mfma_f32_16x16x32_bf16(a[rf], bh0, acc[rf][0], 0, 0, 0);
            acc[rf][1] = __builtin_amdgcn_mfma_f32_16x16x32_bf16(a[rf], bh1, acc[rf][1], 0, 0, 0);
            acc[rf][0] = __builtin_amdgcn_mfma_f32_16x16x32_bf16(a[rf], bl0, acc[rf][0], 0, 0, 0);
            acc[rf][1] = __builtin_amdgcn_mfma_f32_16x16x32_bf16(a[rf], bl1, acc[rf][1], 0, 0, 0);
        }
    }
#pragma unroll
    for (int rf = 0; rf < 8; ++rf) {
#pragma unroll
        for (int rg = 0; rg < 4; ++rg) {
            int row = r0 + rf * 16 + kq * 4 + rg;
            if (row < n) {
                float dn = dinv[row];
                hs[(size_t)row * HID + col0] = f2bf(acc[rf][0][rg] * dn);
                hs[(size_t)row * HID + col1] = f2bf(acc[rf][1][rg] * dn);
            }
        }
    }
}

// ---------------------------------------------------------------------------
// out[d] = maybe_relu( dinv[d] * (hs[d] + sum_{e->d} hs[src]) + bias )  (bf16)
// [round-7/10/12 validated: 66 us, do not touch]
// ---------------------------------------------------------------------------
__device__ __forceinline__ void acc_add(float* acc, u32x4 v) {
    acc[0] += bflo(v.x); acc[1] += bfhi(v.x);
    acc[2] += bflo(v.y); acc[3] += bfhi(v.y);
    acc[4] += bflo(v.z); acc[5] += bfhi(v.z);
    acc[6] += bflo(v.w); acc[7] += bfhi(v.w);
}

__global__ void __launch_bounds__(256) agg_kernel(
        const short* __restrict__ hs, const float* __restrict__ dinv,
        const int* __restrict__ ofs, const int* __restrict__ col,
        const float* __restrict__ bias, short* __restrict__ out,
        int n, int do_relu) {
    int node = blockIdx.x * 4 + (threadIdx.x >> 6);
    if (node >= n) return;
    const int lane = threadIdx.x & 63;
    const int g    = lane >> 4;
    const int sub  = lane & 15;
    const u32x4* __restrict__ rows = (const u32x4*)hs;

    float acc[8] = {0.f, 0.f, 0.f, 0.f, 0.f, 0.f, 0.f, 0.f};
    if (g == 0) {
        u32x4 sv = rows[(size_t)node * 16 + sub];
        acc_add(acc, sv);
    }
    const int e0 = ofs[node], e1 = ofs[node + 1];
    int e = e0;
    for (; e + 16 <= e1; e += 16) {
        int c0 = col[e + g];
        int c1 = col[e + 4 + g];
        int c2 = col[e + 8 + g];
        int c3 = col[e + 12 + g];
        u32x4 v0 = rows[(size_t)c0 * 16 + sub];
        u32x4 v1 = rows[(size_t)c1 * 16 + sub];
        u32x4 v2 = rows[(size_t)c2 * 16 + sub];
        u32x4 v3 = rows[(size_t)c3 * 16 + sub];
        acc_add(acc, v0); acc_add(acc, v1); acc_add(acc, v2); acc_add(acc, v3);
    }
    for (; e + 4 <= e1; e += 4) {
        int c0 = col[e + g];
        u32x4 v0 = rows[(size_t)c0 * 16 + sub];
        acc_add(acc, v0);
    }
    if (e + g < e1) {
        int c0 = col[e + g];
        u32x4 v0 = rows[(size_t)c0 * 16 + sub];
        acc_add(acc, v0);
    }
#pragma unroll
    for (int i = 0; i < 8; ++i) {
        acc[i] += __shfl_xor(acc[i], 16, 64);
        acc[i] += __shfl_xor(acc[i], 32, 64);
    }
    if (g == 0) {
        const float dn = dinv[node];
        float4 b0 = *(const float4*)(bias + 8 * sub);
        float4 b1 = *(const float4*)(bias + 8 * sub + 4);
        float o0 = fmaf(acc[0], dn, b0.x);
        float o1 = fmaf(acc[1], dn, b0.y);
        float o2 = fmaf(acc[2], dn, b0.z);
        float o3 = fmaf(acc[3], dn, b0.w);
        float o4 = fmaf(acc[4], dn, b1.x);
        float o5 = fmaf(acc[5], dn, b1.y);
        float o6 = fmaf(acc[6], dn, b1.z);
        float o7 = fmaf(acc[7], dn, b1.w);
        if (do_relu) {
            o0 = fmaxf(o0, 0.f); o1 = fmaxf(o1, 0.f);
            o2 = fmaxf(o2, 0.f); o3 = fmaxf(o3, 0.f);
            o4 = fmaxf(o4, 0.f); o5 = fmaxf(o5, 0.f);
            o6 = fmaxf(o6, 0.f); o7 = fmaxf(o7, 0.f);
        }
        u32x4 pk;
        pk.x = pk2(o0, o1); pk.y = pk2(o2, o3);
        pk.z = pk2(o4, o5); pk.w = pk2(o6, o7);
        ((u32x4*)out)[(size_t)node * 16 + sub] = pk;
    }
}

// ---------------------------------------------------------------------------
// head: fused mean-pool + MLP (one block per graph)
// ---------------------------------------------------------------------------
__global__ void __launch_bounds__(128) pool_mlp_kernel(
        const short* __restrict__ h, const int* __restrict__ gstart,
        const float* __restrict__ W1, const float* __restrict__ b1,
        const float* __restrict__ W2, const float* __restrict__ b2,
        float* __restrict__ out) {
    __shared__ float p[HID];
    __shared__ float hid[HID];
    int g = blockIdx.x, c = threadIdx.x;
    int s = gstart[g], e = gstart[g + 1];
    float acc = 0.f;
    int i = s;
    for (; i + 4 <= e; i += 4) {
        acc += bf2f(h[(size_t)i * HID + c]) + bf2f(h[(size_t)(i + 1) * HID + c])
             + bf2f(h[(size_t)(i + 2) * HID + c]) + bf2f(h[(size_t)(i + 3) * HID + c]);
    }
    for (; i < e; ++i) acc += bf2f(h[(size_t)i * HID + c]);
    p[c] = acc / fmaxf((float)(e - s), 1.f);
    __syncthreads();
    float a = b1[c];
#pragma unroll 8
    for (int k = 0; k < HID; ++k) a = fmaf(p[k], W1[k * HID + c], a);
    hid[c] = fmaxf(a, 0.f);
    __syncthreads();
    if (c < OUTC) {
        float o = b2[c];
#pragma unroll 8
        for (int k = 0; k < HID; ++k) o = fmaf(hid[k], W2[k * OUTC + c], o);
        out[g * OUTC + c] = o;
    }
}

// ---------------------------------------------------------------------------
extern "C" void kernel_launch(void* const* d_in, const int* in_sizes, int n_in,
                              void* d_out, int out_size, void* d_ws, size_t ws_size,
                              hipStream_t stream) {
    const float* x   = (const float*)d_in[0];
    const int*   ei  = (const int*)d_in[1];
    const int*   bat = (const int*)d_in[2];
    const float* Wc0 = (const float*)d_in[3];
    const float* bc0 = (const float*)d_in[4];
    const float* Wc1 = (const float*)d_in[5];
    const float* bc1 = (const float*)d_in[6];
    const float* Wc2 = (const float*)d_in[7];
    const float* bc2 = (const float*)d_in[8];
    const float* W1  = (const float*)d_in[9];
    const float* b1  = (const float*)d_in[10];
    const float* W2  = (const float*)d_in[11];
    const float* b2  = (const float*)d_in[12];
    float* out = (float*)d_out;

    const int  n = in_sizes[0] / HID;             // 100000 (< 2^20, NBIN <= 400)
    const long E = in_sizes[1] / 2;
    const int  NBIN = (n + PSIZE - 1) / PSIZE;    // 391

    char* w = (char*)d_ws;
    size_t off = 0;
    auto carve = [&](size_t bytes) {
        void* p = w + off;
        off += (bytes + 255) & ~(size_t)255;
        return p;
    };
    int*   cnt     = (int*)carve((size_t)NBIN * NGROUP * 4);
    int*   bofs    = (int*)carve((size_t)(NBIN + 1) * 4);
    int*   ofs     = (int*)carve((size_t)(n + 1) * 4);
    float* dinv    = (float*)carve((size_t)n * 4);
    int*   gstart  = (int*)carve((NGRAPH + 1) * 4);
    int*   col     = (int*)carve((size_t)E * 4);
    short* Wt      = (short*)carve((size_t)3 * 2 * HID * HID * 2);
    uint32_t* binned = (uint32_t*)carve((size_t)NBIN * NGROUP * CAP * 4);  // 25.6 MB
    short* hs      = (short*)carve((size_t)n * HID * 2);
    short* h       = (short*)carve((size_t)n * HID * 2);

    // prep: 3 wprep blocks + boundary blocks (no cnt zeroing needed)
    const int nbb = (n + 255) / 256;
    prep_kernel<<<3 + nbb, 256, 0, stream>>>(ei, bat, Wc0, Wc1, Wc2, Wt, gstart, n);

    bin_scatter_kernel<<<NGROUP, 512, 0, stream>>>(ei, cnt, binned, E, NBIN);
    binscan_kernel<<<1, 1024, 0, stream>>>(cnt, bofs, NBIN);
    bin_build_kernel<<<NBIN, 512, 0, stream>>>(binned, cnt, bofs, ofs, dinv, col,
                                               n, NBIN, E);

    const int gb = (n + 127) / 128;
    const int ab = (n + 3) / 4;
    const size_t WSTRIDE = (size_t)2 * HID * HID;
    // layer 0
    gemm_hs_kernel<true><<<gb, 256, 0, stream>>>(x, Wt, dinv, hs, n);
    agg_kernel<<<ab, 256, 0, stream>>>(hs, dinv, ofs, col, bc0, h, n, 1);
    // layer 1
    gemm_hs_kernel<false><<<gb, 256, 0, stream>>>(h, Wt + WSTRIDE, dinv, hs, n);
    agg_kernel<<<ab, 256, 0, stream>>>(hs, dinv, ofs, col, bc1, h, n, 1);
    // layer 2 (no relu)
    gemm_hs_kernel<false><<<gb, 256, 0, stream>>>(h, Wt + 2 * WSTRIDE, dinv, hs, n);
    agg_kernel<<<ab, 256, 0, stream>>>(hs, dinv, ofs, col, bc2, h, n, 0);

    pool_mlp_kernel<<<NGRAPH, 128, 0, stream>>>(h, gstart, W1, b1, W2, b2, out);
}

// Round 14
// 374.886 us; speedup vs baseline: 1.0026x; 1.0026x over previous
//
#include <hip/hip_runtime.h>
#include <hip/hip_bf16.h>
#include <stdint.h>

#define HID     128
#define OUTC    10
#define NGRAPH  512
#define NGROUP  256        // one writer block per group (1 block/CU)
#define PSIZE   256        // nodes per bin
#define CAP     64         // entries per (bin,group) region (mean 16, +12 sigma)
#define NBIN_MX 400        // compile-time bound (NBIN=391 for n=100000)

using bf16x8 = __attribute__((ext_vector_type(8))) short;
using f32x4  = __attribute__((ext_vector_type(4))) float;
using u32x4  = __attribute__((ext_vector_type(4))) uint32_t;

__device__ __forceinline__ short f2bf(float f) {
    __hip_bfloat16 h = __float2bfloat16(f);
    return *reinterpret_cast<short*>(&h);
}
__device__ __forceinline__ float bf2f(short s) {
    union { uint32_t u; float f; } x; x.u = ((uint32_t)(uint16_t)s) << 16; return x.f;
}
__device__ __forceinline__ float bflo(uint32_t v) {
    union { uint32_t u; float f; } x; x.u = v << 16; return x.f;
}
__device__ __forceinline__ float bfhi(uint32_t v) {
    union { uint32_t u; float f; } x; x.u = v & 0xffff0000u; return x.f;
}
__device__ __forceinline__ uint32_t pk2(float lo, float hi) {
    return (uint32_t)(uint16_t)f2bf(lo) | ((uint32_t)(uint16_t)f2bf(hi) << 16);
}

// Inline int64-vs-int32 layout detection (wave-wide ballot on odd words).
__device__ __forceinline__ int detect_f64(const int* __restrict__ ei) {
    int lane = threadIdx.x & 63;
    int v = ei[2 * lane + 1];
    unsigned long long b = __ballot(v == 0);
    return (b == ~0ULL) ? 1 : 0;
}

__device__ __forceinline__ int fetch_idx(const int* __restrict__ p, long j, int f64) {
    return p[f64 ? (j << 1) : j];
}

// ---------------------------------------------------------------------------
// front: blocks 0-2 -> weight transpose+split (bf16 hi+lo); blocks 3..258 ->
// boundary-detect slice + single-writer LDS-bucketed scatter. One dispatch.
// ---------------------------------------------------------------------------
__global__ void __launch_bounds__(512) front_kernel(
        const int* __restrict__ ei, const int* __restrict__ batch,
        const float* __restrict__ W0, const float* __restrict__ W1,
        const float* __restrict__ W2, short* __restrict__ Wt,
        int* __restrict__ cnt, uint32_t* __restrict__ binned,
        int* __restrict__ gstart, int n, long E, int NBIN) {
    __shared__ int      lcnt[NBIN_MX];
    __shared__ uint32_t lbin[NBIN_MX * CAP];        // 100 KB
    __shared__ float    Ws[64][129];                // 33 KB (wprep blocks only)
    int bid = blockIdx.x;
    const int tid = threadIdx.x;

    if (bid < 3) {                                   // ---- weight prep (512 thr)
        const float* W = (bid == 0) ? W0 : (bid == 1) ? W1 : W2;
        short* hi = Wt + (size_t)bid * 2 * HID * HID;
        short* lo = hi + HID * HID;
        for (int half = 0; half < 2; ++half) {
            const int kbase = half * 64;
#pragma unroll
            for (int it = 0; it < 4; ++it) {         // 2048 float4 loads
                int idx = (tid + it * 512) * 4;
                int k = idx >> 7, c = idx & 127;
                float4 v = *(const float4*)(W + (size_t)(kbase + k) * HID + c);
                Ws[k][c] = v.x; Ws[k][c + 1] = v.y; Ws[k][c + 2] = v.z; Ws[k][c + 3] = v.w;
            }
            __syncthreads();
            const int k2 = tid & 63;
            const int cb = tid >> 6;                 // 0..7
#pragma unroll
            for (int it = 0; it < 16; ++it) {        // transposed writes
                int c = cb + it * 8;
                float w0 = Ws[k2][c];
                short h = f2bf(w0);
                hi[(size_t)c * HID + kbase + k2] = h;
                lo[(size_t)c * HID + kbase + k2] = f2bf(w0 - bf2f(h));
            }
            __syncthreads();
        }
        return;
    }
    const int g = bid - 3;                           // 0..255
    const int f = detect_f64(ei);
    {   // ---- boundary detection slice (batch sorted); 256*512 >= n
        int i = g * 512 + tid;
        if (i < n) {
            int b  = fetch_idx(batch, i, f);
            int bp = (i == 0) ? -1 : fetch_idx(batch, i - 1, f);
            for (int gg = bp + 1; gg <= b; ++gg) gstart[gg] = i;
            if (i == n - 1) {
                for (int gg = b + 1; gg <= NGRAPH; ++gg) gstart[gg] = n;
            }
        }
    }
    // ---- scatter: stream chunk once, LDS buckets, flush to exclusive regions
    for (int b = tid; b < NBIN; b += 512) lcnt[b] = 0;
    __syncthreads();
    const long chunk = (E + NGROUP - 1) / NGROUP;
    const long e0 = (long)g * chunk;
    const long e1 = (e0 + chunk < E) ? e0 + chunk : E;
    for (long e = e0 + tid; e < e1; e += 512) {
        int s = fetch_idx(ei, e, f);
        int d = fetch_idx(ei, E + e, f);
        int b = d >> 8;
        int p = atomicAdd(&lcnt[b], 1);
        if (p < CAP)
            lbin[b * CAP + p] = (uint32_t)s | ((uint32_t)(d & (PSIZE - 1)) << 20);
    }
    __syncthreads();
    const int wv = tid >> 6, lane = tid & 63;
    for (int b = wv; b < NBIN; b += 8) {
        int c = min(lcnt[b], CAP);
        uint32_t* __restrict__ dst = binned + ((size_t)b * NGROUP + g) * CAP;
        for (int i = lane; i < c; i += 64) dst[i] = lbin[b * CAP + i];
        if (lane == 0) cnt[b * NGROUP + g] = c;
    }
}

// ---------------------------------------------------------------------------
// bin totals (wave-per-bin coalesced sums over 256 group counts) + scan.
// ---------------------------------------------------------------------------
__global__ void __launch_bounds__(1024) binscan_kernel(
        const int* __restrict__ cnt, int* __restrict__ bofs, int NBIN) {
    __shared__ int stot[NBIN_MX];
    __shared__ int wsum[16];
    const int tid  = threadIdx.x;
    const int lane = tid & 63;
    const int wid  = tid >> 6;
    for (int b = wid; b < NBIN; b += 16) {
        int s = 0;
#pragma unroll
        for (int i = 0; i < NGROUP / 64; ++i) s += cnt[b * NGROUP + lane + i * 64];
#pragma unroll
        for (int d = 1; d < 64; d <<= 1) s += __shfl_xor(s, d, 64);
        if (lane == 0) stot[b] = s;
    }
    __syncthreads();
    int v = (tid < NBIN) ? stot[tid] : 0;
    int inc = v;
#pragma unroll
    for (int d = 1; d < 64; d <<= 1) {
        int t = __shfl_up(inc, d, 64);
        if (lane >= d) inc += t;
    }
    if (lane == 63) wsum[wid] = inc;
    __syncthreads();
    if (wid == 0) {
        int ws = (lane < 16) ? wsum[lane] : 0;
        int winc = ws;
#pragma unroll
        for (int d = 1; d < 16; d <<= 1) {
            int t = __shfl_up(winc, d, 64);
            if (lane >= d) winc += t;
        }
        if (lane < 16) wsum[lane] = winc - ws;
    }
    __syncthreads();
    int excl = wsum[wid] + (inc - v);
    if (tid <= NBIN) bofs[tid] = excl;
}

// ---------------------------------------------------------------------------
// CSR pass B: one block per bin; LDS histogram -> scan -> scatter; ofs + dinv.
// ---------------------------------------------------------------------------
__global__ void __launch_bounds__(512) bin_build_kernel(
        const uint32_t* __restrict__ binned, const int* __restrict__ cnt,
        const int* __restrict__ bofs, int* __restrict__ ofs,
        float* __restrict__ dinv, int* __restrict__ col,
        int n, int NBIN, long E) {
    __shared__ int lcnt[PSIZE];
    __shared__ int lofs[PSIZE];
    __shared__ int lrank[PSIZE];
    __shared__ int wtot[4];
    const int b    = blockIdx.x;
    const int v0   = b * PSIZE;
    const int nn   = min(PSIZE, n - v0);
    const int tid  = threadIdx.x;
    const int wv   = tid >> 6;
    const int lane = tid & 63;
    if (tid < PSIZE) { lcnt[tid] = 0; lrank[tid] = 0; }
    __syncthreads();
    for (int sg = wv; sg < NGROUP; sg += 8) {
        const int c = min(cnt[b * NGROUP + sg], CAP);
        const uint32_t* __restrict__ src = binned + ((size_t)b * NGROUP + sg) * CAP;
        for (int i = lane; i < c; i += 64)
            atomicAdd(&lcnt[src[i] >> 20], 1);
    }
    __syncthreads();
    if (tid < PSIZE) {
        int v = lcnt[tid];
        int inc = v;
#pragma unroll
        for (int d = 1; d < 64; d <<= 1) {
            int t = __shfl_up(inc, d, 64);
            if (lane >= d) inc += t;
        }
        if (lane == 63) wtot[wv] = inc;
        lofs[tid] = inc - v;
    }
    __syncthreads();
    if (tid < PSIZE) {
        int add = 0;
#pragma unroll
        for (int k = 0; k < 4; ++k) if (k < wv) add += wtot[k];
        lofs[tid] += add;
    }
    __syncthreads();
    const int base = bofs[b];
    for (int sg = wv; sg < NGROUP; sg += 8) {
        const int c = min(cnt[b * NGROUP + sg], CAP);
        const uint32_t* __restrict__ src = binned + ((size_t)b * NGROUP + sg) * CAP;
        for (int i = lane; i < c; i += 64) {
            uint32_t v = src[i];
            int dl = (int)(v >> 20);
            int rk = atomicAdd(&lrank[dl], 1);
            col[base + lofs[dl] + rk] = (int)(v & 0xFFFFFu);
        }
    }
    if (tid < nn) {
        ofs[v0 + tid]  = base + lofs[tid];
        dinv[v0 + tid] = rsqrtf((float)lcnt[tid] + 1.0f);
    }
    if (tid == 0 && v0 + nn == n) ofs[n] = (int)E;
}

// ---------------------------------------------------------------------------
// hs = bf16( (A @ W) * dinv[:,None] ) — MFMA bf16, split-W hi+lo.
// A tile staged once in LDS with chunk-XOR swizzle.  [round-12 validated]
// bf16 layers use global_load_lds: per-lane pre-swizzled GLOBAL src +
// wave-uniform linear LDS dest (lane x 16B appended by HW) -> identical LDS
// contents to the reg-staged path, no VGPR round-trip.
// ---------------------------------------------------------------------------
template<bool AFP32>
__global__ void __launch_bounds__(256) gemm_hs_kernel(
        const void* __restrict__ Ap, const short* __restrict__ Wt,
        const float* __restrict__ dinv, short* __restrict__ hs, int n) {
    __shared__ __attribute__((aligned(16))) short As[128 * 128];  // 32 KB
    const short* __restrict__ Bh = Wt;
    const short* __restrict__ Bl = Wt + HID * HID;
    const int tid = threadIdx.x;
    const int w  = tid >> 6;
    const int l  = tid & 63;
    const int lr = l & 15;
    const int kq = l >> 4;
    const int r0 = blockIdx.x * 128;

    const float* Af = (const float*)Ap;
    const short* Ab = (const short*)Ap;

    if (AFP32) {
#pragma unroll
        for (int it = 0; it < 8; ++it) {
            int ci  = tid + it * 256;
            int row = ci >> 4, c = ci & 15;
            int rg  = r0 + row; if (rg >= n) rg = n - 1;
            const float* ap = Af + (size_t)rg * HID + c * 8;
            float4 f0 = *(const float4*)ap;
            float4 f1 = *(const float4*)(ap + 4);
            bf16x8 tv;
            tv[0] = f2bf(f0.x); tv[1] = f2bf(f0.y); tv[2] = f2bf(f0.z); tv[3] = f2bf(f0.w);
            tv[4] = f2bf(f1.x); tv[5] = f2bf(f1.y); tv[6] = f2bf(f1.z); tv[7] = f2bf(f1.w);
            *(bf16x8*)(As + row * 128 + ((c ^ (row & 15)) << 3)) = tv;
        }
    } else {
#if __has_builtin(__builtin_amdgcn_global_load_lds)
#pragma unroll
        for (int it = 0; it < 8; ++it) {
            int ci  = tid + it * 256;
            int row = ci >> 4, c = ci & 15;
            int rg  = r0 + row; if (rg >= n) rg = n - 1;
            // swizzled global source; linear LDS dest (HW adds lane*16)
            const short* gsrc = Ab + (size_t)rg * HID + ((c ^ (row & 15)) << 3);
            short* ldst = As + (size_t)((tid & ~63) + it * 256) * 8;
            __builtin_amdgcn_global_load_lds(
                (const __attribute__((address_space(1))) uint32_t*)gsrc,
                (__attribute__((address_space(3))) uint32_t*)ldst,
                16, 0, 0);
        }
#else
#pragma unroll
        for (int it = 0; it < 8; ++it) {
            int ci  = tid + it * 256;
            int row = ci >> 4, c = ci & 15;
            int rg  = r0 + row; if (rg >= n) rg = n - 1;
            bf16x8 tv = *(const bf16x8*)(Ab + (size_t)rg * HID + c * 8);
            *(bf16x8*)(As + row * 128 + ((c ^ (row & 15)) << 3)) = tv;
        }
#endif
    }
    __syncthreads();

    f32x4 acc[8][2] = {};
    const int col0 = w * 32 + lr;
    const int col1 = w * 32 + 16 + lr;

#pragma unroll
    for (int ks = 0; ks < 4; ++ks) {
        const int k0 = ks * 32 + kq * 8;
        bf16x8 a[8];
#pragma unroll
        for (int rf = 0; rf < 8; ++rf) {
            int row = rf * 16 + lr;      // row & 15 == lr
            a[rf] = *(const bf16x8*)(As + row * 128 + (((ks * 4 + kq) ^ lr) << 3));
        }
        bf16x8 bh0 = *(const bf16x8*)(Bh + (size_t)col0 * HID + k0);
        bf16x8 bh1 = *(const bf16x8*)(Bh + (size_t)col1 * HID + k0);
        bf16x8 bl0 = *(const bf16x8*)(Bl + (size_t)col0 * HID + k0);
        bf16x8 bl1 = *(const bf16x8*)(Bl + (size_t)col1 * HID + k0);
#pragma unroll
        for (int rf = 0; rf < 8; ++rf) {
            acc[rf][0] = __builtin_amdgcn_mfma_f32_16x16x32_bf16(a[rf], bh0, acc[rf][0], 0, 0, 0);
            acc[rf][1] = __builtin_amdgcn_mfma_f32_16x16x32_bf16(a[rf], bh1, acc[rf][1], 0, 0, 0);
            acc[rf][0] = __builtin_amdgcn_mfma_f32_16x16x32_bf16(a[rf], bl0, acc[rf][0], 0, 0, 0);
            acc[rf][1] = __builtin_amdgcn_mfma_f32_16x16x32_bf16(a[rf], bl1, acc[rf][1], 0, 0, 0);
        }
    }
#pragma unroll
    for (int rf = 0; rf < 8; ++rf) {
#pragma unroll
        for (int rg = 0; rg < 4; ++rg) {
            int row = r0 + rf * 16 + kq * 4 + rg;
            if (row < n) {
                float dn = dinv[row];
                hs[(size_t)row * HID + col0] = f2bf(acc[rf][0][rg] * dn);
                hs[(size_t)row * HID + col1] = f2bf(acc[rf][1][rg] * dn);
            }
        }
    }
}

// ---------------------------------------------------------------------------
// out[d] = maybe_relu( dinv[d] * (hs[d] + sum_{e->d} hs[src]) + bias )  (bf16)
// [round-7/10/12/13 validated: 66 us, byte-identical — do not touch]
// ---------------------------------------------------------------------------
__device__ __forceinline__ void acc_add(float* acc, u32x4 v) {
    acc[0] += bflo(v.x); acc[1] += bfhi(v.x);
    acc[2] += bflo(v.y); acc[3] += bfhi(v.y);
    acc[4] += bflo(v.z); acc[5] += bfhi(v.z);
    acc[6] += bflo(v.w); acc[7] += bfhi(v.w);
}

__global__ void __launch_bounds__(256) agg_kernel(
        const short* __restrict__ hs, const float* __restrict__ dinv,
        const int* __restrict__ ofs, const int* __restrict__ col,
        const float* __restrict__ bias, short* __restrict__ out,
        int n, int do_relu) {
    int node = blockIdx.x * 4 + (threadIdx.x >> 6);
    if (node >= n) return;
    const int lane = threadIdx.x & 63;
    const int g    = lane >> 4;
    const int sub  = lane & 15;
    const u32x4* __restrict__ rows = (const u32x4*)hs;

    float acc[8] = {0.f, 0.f, 0.f, 0.f, 0.f, 0.f, 0.f, 0.f};
    if (g == 0) {
        u32x4 sv = rows[(size_t)node * 16 + sub];
        acc_add(acc, sv);
    }
    const int e0 = ofs[node], e1 = ofs[node + 1];
    int e = e0;
    for (; e + 16 <= e1; e += 16) {
        int c0 = col[e + g];
        int c1 = col[e + 4 + g];
        int c2 = col[e + 8 + g];
        int c3 = col[e + 12 + g];
        u32x4 v0 = rows[(size_t)c0 * 16 + sub];
        u32x4 v1 = rows[(size_t)c1 * 16 + sub];
        u32x4 v2 = rows[(size_t)c2 * 16 + sub];
        u32x4 v3 = rows[(size_t)c3 * 16 + sub];
        acc_add(acc, v0); acc_add(acc, v1); acc_add(acc, v2); acc_add(acc, v3);
    }
    for (; e + 4 <= e1; e += 4) {
        int c0 = col[e + g];
        u32x4 v0 = rows[(size_t)c0 * 16 + sub];
        acc_add(acc, v0);
    }
    if (e + g < e1) {
        int c0 = col[e + g];
        u32x4 v0 = rows[(size_t)c0 * 16 + sub];
        acc_add(acc, v0);
    }
#pragma unroll
    for (int i = 0; i < 8; ++i) {
        acc[i] += __shfl_xor(acc[i], 16, 64);
        acc[i] += __shfl_xor(acc[i], 32, 64);
    }
    if (g == 0) {
        const float dn = dinv[node];
        float4 b0 = *(const float4*)(bias + 8 * sub);
        float4 b1 = *(const float4*)(bias + 8 * sub + 4);
        float o0 = fmaf(acc[0], dn, b0.x);
        float o1 = fmaf(acc[1], dn, b0.y);
        float o2 = fmaf(acc[2], dn, b0.z);
        float o3 = fmaf(acc[3], dn, b0.w);
        float o4 = fmaf(acc[4], dn, b1.x);
        float o5 = fmaf(acc[5], dn, b1.y);
        float o6 = fmaf(acc[6], dn, b1.z);
        float o7 = fmaf(acc[7], dn, b1.w);
        if (do_relu) {
            o0 = fmaxf(o0, 0.f); o1 = fmaxf(o1, 0.f);
            o2 = fmaxf(o2, 0.f); o3 = fmaxf(o3, 0.f);
            o4 = fmaxf(o4, 0.f); o5 = fmaxf(o5, 0.f);
            o6 = fmaxf(o6, 0.f); o7 = fmaxf(o7, 0.f);
        }
        u32x4 pk;
        pk.x = pk2(o0, o1); pk.y = pk2(o2, o3);
        pk.z = pk2(o4, o5); pk.w = pk2(o6, o7);
        ((u32x4*)out)[(size_t)node * 16 + sub] = pk;
    }
}

// ---------------------------------------------------------------------------
// head: fused mean-pool + MLP (one block per graph)
// ---------------------------------------------------------------------------
__global__ void __launch_bounds__(128) pool_mlp_kernel(
        const short* __restrict__ h, const int* __restrict__ gstart,
        const float* __restrict__ W1, const float* __restrict__ b1,
        const float* __restrict__ W2, const float* __restrict__ b2,
        float* __restrict__ out) {
    __shared__ float p[HID];
    __shared__ float hid[HID];
    int g = blockIdx.x, c = threadIdx.x;
    int s = gstart[g], e = gstart[g + 1];
    float acc = 0.f;
    int i = s;
    for (; i + 4 <= e; i += 4) {
        acc += bf2f(h[(size_t)i * HID + c]) + bf2f(h[(size_t)(i + 1) * HID + c])
             + bf2f(h[(size_t)(i + 2) * HID + c]) + bf2f(h[(size_t)(i + 3) * HID + c]);
    }
    for (; i < e; ++i) acc += bf2f(h[(size_t)i * HID + c]);
    p[c] = acc / fmaxf((float)(e - s), 1.f);
    __syncthreads();
    float a = b1[c];
#pragma unroll 8
    for (int k = 0; k < HID; ++k) a = fmaf(p[k], W1[k * HID + c], a);
    hid[c] = fmaxf(a, 0.f);
    __syncthreads();
    if (c < OUTC) {
        float o = b2[c];
#pragma unroll 8
        for (int k = 0; k < HID; ++k) o = fmaf(hid[k], W2[k * OUTC + c], o);
        out[g * OUTC + c] = o;
    }
}

// ---------------------------------------------------------------------------
extern "C" void kernel_launch(void* const* d_in, const int* in_sizes, int n_in,
                              void* d_out, int out_size, void* d_ws, size_t ws_size,
                              hipStream_t stream) {
    const float* x   = (const float*)d_in[0];
    const int*   ei  = (const int*)d_in[1];
    const int*   bat = (const int*)d_in[2];
    const float* Wc0 = (const float*)d_in[3];
    const float* bc0 = (const float*)d_in[4];
    const float* Wc1 = (const float*)d_in[5];
    const float* bc1 = (const float*)d_in[6];
    const float* Wc2 = (const float*)d_in[7];
    const float* bc2 = (const float*)d_in[8];
    const float* W1  = (const float*)d_in[9];
    const float* b1  = (const float*)d_in[10];
    const float* W2  = (const float*)d_in[11];
    const float* b2  = (const float*)d_in[12];
    float* out = (float*)d_out;

    const int  n = in_sizes[0] / HID;             // 100000 (< 2^20, NBIN <= 400)
    const long E = in_sizes[1] / 2;
    const int  NBIN = (n + PSIZE - 1) / PSIZE;    // 391

    char* w = (char*)d_ws;
    size_t off = 0;
    auto carve = [&](size_t bytes) {
        void* p = w + off;
        off += (bytes + 255) & ~(size_t)255;
        return p;
    };
    int*   cnt     = (int*)carve((size_t)NBIN * NGROUP * 4);
    int*   bofs    = (int*)carve((size_t)(NBIN + 1) * 4);
    int*   ofs     = (int*)carve((size_t)(n + 1) * 4);
    float* dinv    = (float*)carve((size_t)n * 4);
    int*   gstart  = (int*)carve((NGRAPH + 1) * 4);
    int*   col     = (int*)carve((size_t)E * 4);
    short* Wt      = (short*)carve((size_t)3 * 2 * HID * HID * 2);
    uint32_t* binned = (uint32_t*)carve((size_t)NBIN * NGROUP * CAP * 4);  // 25.6 MB
    short* hs      = (short*)carve((size_t)n * HID * 2);
    short* h       = (short*)carve((size_t)n * HID * 2);

    // front: 3 wprep blocks + 256 boundary+scatter blocks, one dispatch
    front_kernel<<<3 + NGROUP, 512, 0, stream>>>(ei, bat, Wc0, Wc1, Wc2, Wt,
                                                 cnt, binned, gstart, n, E, NBIN);
    binscan_kernel<<<1, 1024, 0, stream>>>(cnt, bofs, NBIN);
    bin_build_kernel<<<NBIN, 512, 0, stream>>>(binned, cnt, bofs, ofs, dinv, col,
                                               n, NBIN, E);

    const int gb = (n + 127) / 128;
    const int ab = (n + 3) / 4;
    const size_t WSTRIDE = (size_t)2 * HID * HID;
    // layer 0
    gemm_hs_kernel<true><<<gb, 256, 0, stream>>>(x, Wt, dinv, hs, n);
    agg_kernel<<<ab, 256, 0, stream>>>(hs, dinv, ofs, col, bc0, h, n, 1);
    // layer 1
    gemm_hs_kernel<false><<<gb, 256, 0, stream>>>(h, Wt + WSTRIDE, dinv, hs, n);
    agg_kernel<<<ab, 256, 0, stream>>>(hs, dinv, ofs, col, bc1, h, n, 1);
    // layer 2 (no relu)
    gemm_hs_kernel<false><<<gb, 256, 0, stream>>>(h, Wt + 2 * WSTRIDE, dinv, hs, n);
    agg_kernel<<<ab, 256, 0, stream>>>(hs, dinv, ofs, col, bc2, h, n, 0);

    pool_mlp_kernel<<<NGRAPH, 128, 0, stream>>>(h, gstart, W1, b1, W2, b2, out);
}